// Round 1
// baseline (1137.756 us; speedup 1.0000x reference)
//
#include <hip/hip_runtime.h>

// SpectralAttention: B=1024, S=3, A=256, D=256
//   s_in[b,a]    = dot(input[b,a,:],      w[:D])
//   s_sc[b,s,a]  = dot(scattered[b,s,a,:], w[D:])
//   scores = prelu(s_in + s_sc); out = softmax over s
//
// Memory-bound: 1.07 GB read / 3 MB write. One wave per (b,a) pair;
// lane i reads float4 at d=i*4 (row = exactly 64*16B = 1 KiB, fully
// coalesced), butterfly-reduce 4 partial dots in one 6-round shuffle tree.

constexpr int kB = 1024;
constexpr int kS = 3;
constexpr int kA = 256;
constexpr int kD = 256;

__global__ __launch_bounds__(256) void spectral_attention_kernel(
    const float* __restrict__ input,      // [B, A, D]
    const float* __restrict__ scattered,  // [B, S, A, D]
    const float* __restrict__ w,          // [2*D]
    const float* __restrict__ prelu,      // [1]
    float* __restrict__ out)              // [B, S, A]
{
    const int gwave = (int)((blockIdx.x * blockDim.x + threadIdx.x) >> 6);
    const int lane  = threadIdx.x & 63;
    const int b = gwave >> 8;    // / kA
    const int a = gwave & 255;   // % kA

    // Per-lane weight chunks (L2/L3 resident after first touch)
    const float4 w1 = *(const float4*)(w + lane * 4);
    const float4 w2 = *(const float4*)(w + kD + lane * 4);

    // input row partial dot
    const float4 xi = *(const float4*)(input + ((size_t)b * kA + a) * kD + lane * 4);
    float p_in = xi.x * w1.x + xi.y * w1.y + xi.z * w1.z + xi.w * w1.w;

    // scattered rows partial dots
    float p_sc[kS];
#pragma unroll
    for (int s = 0; s < kS; ++s) {
        const float4 xs = *(const float4*)(
            scattered + (((size_t)b * kS + s) * kA + a) * (size_t)kD + lane * 4);
        p_sc[s] = xs.x * w2.x + xs.y * w2.y + xs.z * w2.z + xs.w * w2.w;
    }

    // Butterfly reduction across the 64-lane wave: all 4 partials together.
#pragma unroll
    for (int off = 32; off >= 1; off >>= 1) {
        p_in += __shfl_xor(p_in, off, 64);
#pragma unroll
        for (int s = 0; s < kS; ++s) p_sc[s] += __shfl_xor(p_sc[s], off, 64);
    }

    // scores + PReLU + softmax over S=3 (all lanes have full sums)
    const float alpha = prelu[0];
    float sc[kS];
#pragma unroll
    for (int s = 0; s < kS; ++s) {
        const float v = p_in + p_sc[s];
        sc[s] = v >= 0.0f ? v : alpha * v;
    }
    const float m  = fmaxf(sc[0], fmaxf(sc[1], sc[2]));
    const float e0 = __expf(sc[0] - m);
    const float e1 = __expf(sc[1] - m);
    const float e2 = __expf(sc[2] - m);
    const float inv = 1.0f / (e0 + e1 + e2);

    if (lane < kS) {
        const float e = (lane == 0) ? e0 : ((lane == 1) ? e1 : e2);
        out[((size_t)b * kS + lane) * kA + a] = e * inv;
    }
}

extern "C" void kernel_launch(void* const* d_in, const int* in_sizes, int n_in,
                              void* d_out, int out_size, void* d_ws, size_t ws_size,
                              hipStream_t stream) {
    const float* input     = (const float*)d_in[0];
    const float* scattered = (const float*)d_in[1];
    const float* w         = (const float*)d_in[2];
    const float* prelu     = (const float*)d_in[3];
    float* out             = (float*)d_out;

    // One wave per (b,a): B*A waves = 262144; 4 waves/block -> 65536 blocks.
    const int total_waves = kB * kA;
    const int blocks = total_waves / 4;
    spectral_attention_kernel<<<blocks, 256, 0, stream>>>(input, scattered, w, prelu, out);
}